// Round 1
// baseline (329.022 us; speedup 1.0000x reference)
//
#include <hip/hip_runtime.h>

// Problem constants
#define B_SZ   64
#define IC_N   128
#define OC_N   128
#define OUT_D  1024
#define L_N    2048

// Tiling
#define D_TILE 8    // d positions per block (16 consecutive floats of L per (b,i) row)
#define N_TILE 32   // OC per block (OC split x4)
#define KC     16   // input channels per K-chunk -> K=32 per chunk (one MFMA K-step)
#define KPAD   40   // LDS row stride in bf16 (32 + 8 pad: 80B stride -> <=2-way bank aliasing)

typedef __attribute__((ext_vector_type(8))) __bf16          bf16x8;
typedef __attribute__((ext_vector_type(8))) unsigned short  u16x8;
typedef __attribute__((ext_vector_type(4))) float           f32x4;

// RNE fp32->bf16, packed pair (lo in low 16 bits). Inputs are finite normals.
__device__ __forceinline__ unsigned pack2bf(float lo, float hi) {
    unsigned ul = __builtin_bit_cast(unsigned, lo);
    unsigned uh = __builtin_bit_cast(unsigned, hi);
    ul += 0x7fffu + ((ul >> 16) & 1u);
    uh += 0x7fffu + ((uh >> 16) & 1u);
    return (ul >> 16) | (uh & 0xffff0000u);
}

__global__ __launch_bounds__(256, 2)
void lc1d_kernel(const float* __restrict__ x, const float* __restrict__ w,
                 float* __restrict__ out) {
    // LDS: per-d bf16 tiles, K-contiguous rows, padded stride
    __shared__ __align__(16) unsigned short Xs[D_TILE][B_SZ][KPAD];   // 40 KB
    __shared__ __align__(16) unsigned short Ws[D_TILE][N_TILE][KPAD]; // 20 KB

    const int t     = threadIdx.x;
    const int wv_id = t >> 6;        // wave 0..3, owns d-pair {2w, 2w+1}
    const int lane  = t & 63;
    const int col   = lane & 15;     // MFMA free-dim index within 16-tile
    const int quad  = lane >> 4;     // MFMA k-group / row-group

    const int oc_blk = blockIdx.x & 3;
    const int dg     = blockIdx.x >> 2;      // 128 d-groups
    const int o0     = oc_blk * N_TILE;
    const int l0     = dg * (2 * D_TILE);    // start offset in L (=dg*16)

    f32x4 acc[2][4][2];
#pragma unroll
    for (int dl = 0; dl < 2; ++dl)
#pragma unroll
        for (int mt = 0; mt < 4; ++mt)
#pragma unroll
            for (int nt = 0; nt < 2; ++nt)
                acc[dl][mt][nt] = (f32x4){0.f, 0.f, 0.f, 0.f};

    for (int chunk = 0; chunk < IC_N / KC; ++chunk) {
        const int i0 = chunk * KC;

        // ---- global loads (issued before barrier: overlap previous chunk's MFMA) ----
        // X: 64 b x 16 i x 16 floats = 4096 float4 -> 16/thread
        float4 xv[16];
#pragma unroll
        for (int r = 0; r < 16; ++r) {
            const int f  = t + 256 * r;
            const int b  = f >> 6;
            const int il = (f >> 2) & 15;
            const int j  = f & 3;
            xv[r] = *(const float4*)&x[(size_t)(b * IC_N + i0 + il) * L_N + l0 + 4 * j];
        }
        // W: 32 o x 16 i x 16 floats = 2048 float4 -> 8/thread
        float4 wvv[8];
#pragma unroll
        for (int r = 0; r < 8; ++r) {
            const int f  = t + 256 * r;
            const int ol = f >> 6;
            const int il = (f >> 2) & 15;
            const int j  = f & 3;
            wvv[r] = *(const float4*)&w[(size_t)((o0 + ol) * IC_N + i0 + il) * L_N + l0 + 4 * j];
        }

        __syncthreads();  // previous chunk's LDS reads complete before overwrite

        // ---- convert + LDS store ----
        // float4 = {(dd=2j,s=0),(2j,s=1),(2j+1,s=0),(2j+1,s=1)}; k = 2*il + s
#pragma unroll
        for (int r = 0; r < 16; ++r) {
            const int f  = t + 256 * r;
            const int b  = f >> 6;
            const int il = (f >> 2) & 15;
            const int j  = f & 3;
            *(unsigned*)&Xs[2 * j][b][2 * il]     = pack2bf(xv[r].x, xv[r].y);
            *(unsigned*)&Xs[2 * j + 1][b][2 * il] = pack2bf(xv[r].z, xv[r].w);
        }
#pragma unroll
        for (int r = 0; r < 8; ++r) {
            const int f  = t + 256 * r;
            const int ol = f >> 6;
            const int il = (f >> 2) & 15;
            const int j  = f & 3;
            *(unsigned*)&Ws[2 * j][ol][2 * il]     = pack2bf(wvv[r].x, wvv[r].y);
            *(unsigned*)&Ws[2 * j + 1][ol][2 * il] = pack2bf(wvv[r].z, wvv[r].w);
        }

        __syncthreads();

        // ---- MFMA: per owned d, C(64x32) += X(64x32k) * W(32x32k)^T ----
#pragma unroll
        for (int dl = 0; dl < 2; ++dl) {
            const int dp = 2 * wv_id + dl;
            bf16x8 afr[4];
            bf16x8 bfr[2];
#pragma unroll
            for (int mt = 0; mt < 4; ++mt)
                afr[mt] = __builtin_bit_cast(bf16x8,
                    *(const u16x8*)&Xs[dp][16 * mt + col][quad * 8]);
#pragma unroll
            for (int nt = 0; nt < 2; ++nt)
                bfr[nt] = __builtin_bit_cast(bf16x8,
                    *(const u16x8*)&Ws[dp][16 * nt + col][quad * 8]);
#pragma unroll
            for (int mt = 0; mt < 4; ++mt)
#pragma unroll
                for (int nt = 0; nt < 2; ++nt)
                    acc[dl][mt][nt] = __builtin_amdgcn_mfma_f32_16x16x32_bf16(
                        afr[mt], bfr[nt], acc[dl][mt][nt], 0, 0, 0);
        }
    }

    // ---- epilogue: scale by 1/sqrt(IC); d-pair per wave -> float2 stores ----
    const float scale = 0.088388347648318447f;  // 1/sqrt(128)
    const int dbase = dg * D_TILE + 2 * wv_id;
#pragma unroll
    for (int mt = 0; mt < 4; ++mt)
#pragma unroll
        for (int nt = 0; nt < 2; ++nt)
#pragma unroll
            for (int reg = 0; reg < 4; ++reg) {
                const int b = 16 * mt + 4 * quad + reg;  // C/D: row = quad*4 + reg
                const int o = o0 + 16 * nt + col;        // C/D: col = lane&15
                float2 v;
                v.x = acc[0][mt][nt][reg] * scale;
                v.y = acc[1][mt][nt][reg] * scale;
                *(float2*)&out[(size_t)(b * OC_N + o) * OUT_D + dbase] = v;
            }
}

extern "C" void kernel_launch(void* const* d_in, const int* in_sizes, int n_in,
                              void* d_out, int out_size, void* d_ws, size_t ws_size,
                              hipStream_t stream) {
    const float* x = (const float*)d_in[0];
    const float* w = (const float*)d_in[1];
    float* out     = (float*)d_out;

    dim3 grid(512);   // 128 d-groups x 4 OC chunks = 2 blocks/CU exactly
    dim3 block(256);  // 4 waves
    hipLaunchKernelGGL(lc1d_kernel, grid, block, 0, stream, x, w, out);
}